// Round 9
// baseline (479.429 us; speedup 1.0000x reference)
//
#include <hip/hip_runtime.h>
#include <hip/hip_fp16.h>

typedef __attribute__((ext_vector_type(8))) _Float16 f16x8;
typedef __attribute__((ext_vector_type(8))) unsigned short u16x8;
typedef __attribute__((ext_vector_type(4))) float f32x4;

#define DEV __device__ __forceinline__

DEV unsigned short f2h(float f) {
  _Float16 h = (_Float16)f;
  return __builtin_bit_cast(unsigned short, h);
}
DEV float h2f(unsigned short u) {
  return (float)__builtin_bit_cast(_Float16, u);
}

#if __has_builtin(__builtin_amdgcn_fdot2)
typedef __attribute__((ext_vector_type(2))) _Float16 f16x2;
DEV float fdot2u(unsigned a, unsigned b, float c) {
  return __builtin_amdgcn_fdot2(__builtin_bit_cast(f16x2, a),
                                __builtin_bit_cast(f16x2, b), c, false);
}
#else
DEV float fdot2u(unsigned a, unsigned b, float c) {
  __half2 ha = __builtin_bit_cast(__half2, a);
  __half2 hb = __builtin_bit_cast(__half2, b);
  return c + __low2float(ha) * __low2float(hb) + __high2float(ha) * __high2float(hb);
}
#endif

// ---------------------------------------------------------------- prep
__global__ __launch_bounds__(256) void k_prep(const float* __restrict__ W0, const float* __restrict__ W1,
                                              const float* __restrict__ W2, const float* __restrict__ W3,
                                              const float* __restrict__ W4,
                                              unsigned short* __restrict__ T0, unsigned short* __restrict__ T1,
                                              unsigned short* __restrict__ T2, unsigned short* __restrict__ T3,
                                              unsigned short* __restrict__ T4,
                                              const unsigned* __restrict__ raw, int* __restrict__ canon) {
  int mat = blockIdx.y;
  const float* W = (mat == 0) ? W0 : (mat == 1) ? W1 : (mat == 2) ? W2 : (mat == 3) ? W3 : W4;
  unsigned short* T = (mat == 0) ? T0 : (mat == 1) ? T1 : (mat == 2) ? T2 : (mat == 3) ? T3 : T4;
  int tx = blockIdx.x & 7, ty = blockIdx.x >> 3;
  __shared__ float tile[64][65];
  int t = threadIdx.x;
  int r = t >> 6, c = t & 63;
#pragma unroll
  for (int i = 0; i < 16; ++i)
    tile[r + i * 4][c] = W[(size_t)(ty * 64 + r + i * 4) * 512 + tx * 64 + c];
  __syncthreads();
#pragma unroll
  for (int i = 0; i < 16; ++i)
    T[(size_t)(tx * 64 + r + i * 4) * 512 + ty * 64 + c] = f2h(tile[c][r + i * 4]);

  if (mat == 0 && blockIdx.x == 0) {
    __shared__ int s_gt1, s_f32;
    if (t == 0) { s_gt1 = 0; s_f32 = 0; }
    __syncthreads();
    int gt1 = 0, fv = 0;
    for (int i = t; i < 512; i += 256) {
      unsigned v = raw[i];
      if (v == 0x3F800000u) fv = 1;
      else if (v > 1u) gt1 = 1;
    }
    if (gt1) s_gt1 = 1;
    if (fv)  s_f32 = 1;
    __syncthreads();
    int mode = s_gt1 ? 1 : (s_f32 ? 2 : 0);
    for (int i = t; i < 2048; i += 256) {
      int v;
      if (mode == 1)      v = ((const unsigned char*)raw)[i] ? 1 : 0;
      else if (mode == 2) v = (((const float*)raw)[i] != 0.f) ? 1 : 0;
      else                v = raw[i] ? 1 : 0;
      canon[i] = v;
    }
  }
}

// ---------------------------------------------------------------- layernorm -> f16
__global__ __launch_bounds__(64) void k_ln(const float* __restrict__ s,
                                           const float* __restrict__ gamma,
                                           const float* __restrict__ beta,
                                           unsigned short* __restrict__ sn) {
  int row = blockIdx.x, l = threadIdx.x;
  const float* sr = s + (size_t)row * 512 + l * 8;
  float4 x0 = *(const float4*)sr, x1 = *(const float4*)(sr + 4);
  float sum = x0.x + x0.y + x0.z + x0.w + x1.x + x1.y + x1.z + x1.w;
  float sq  = x0.x*x0.x + x0.y*x0.y + x0.z*x0.z + x0.w*x0.w
            + x1.x*x1.x + x1.y*x1.y + x1.z*x1.z + x1.w*x1.w;
#pragma unroll
  for (int off = 32; off >= 1; off >>= 1) {
    sum += __shfl_xor(sum, off);
    sq  += __shfl_xor(sq, off);
  }
  float mu = sum * (1.f / 512.f);
  float rstd = rsqrtf(sq * (1.f / 512.f) - mu * mu + 1e-5f);
  float4 g0 = *(const float4*)(gamma + l * 8), g1 = *(const float4*)(gamma + l * 8 + 4);
  float4 b0 = *(const float4*)(beta + l * 8),  b1 = *(const float4*)(beta + l * 8 + 4);
  u16x8 o;
  o[0] = f2h((x0.x - mu) * rstd * g0.x + b0.x);
  o[1] = f2h((x0.y - mu) * rstd * g0.y + b0.y);
  o[2] = f2h((x0.z - mu) * rstd * g0.z + b0.z);
  o[3] = f2h((x0.w - mu) * rstd * g0.w + b0.w);
  o[4] = f2h((x1.x - mu) * rstd * g1.x + b1.x);
  o[5] = f2h((x1.y - mu) * rstd * g1.y + b1.y);
  o[6] = f2h((x1.z - mu) * rstd * g1.z + b1.z);
  o[7] = f2h((x1.w - mu) * rstd * g1.w + b1.w);
  *(u16x8*)(sn + (size_t)row * 512 + l * 8) = o;
}

// ---------------------------------------------------------------- direct-fragment GEMM
DEV void gemm_direct(const unsigned short* __restrict__ A,
                     const unsigned short* __restrict__ Wt,
                     const float* __restrict__ bvec,
                     void* __restrict__ outp,
                     const float* __restrict__ gate,
                     int mode, int ct, int rt) {
  int t = threadIdx.x, l = t & 63, w = t >> 6;
  int lane15 = l & 15, g = l >> 4;
  int wr = w >> 1, wc = w & 1;
  const unsigned short* ap[4];
  const unsigned short* bp[2];
#pragma unroll
  for (int mt = 0; mt < 4; ++mt)
    ap[mt] = A + (size_t)(rt * 128 + wr * 64 + mt * 16 + lane15) * 512 + g * 8;
#pragma unroll
  for (int nt = 0; nt < 2; ++nt)
    bp[nt] = Wt + (size_t)(ct * 64 + wc * 32 + nt * 16 + lane15) * 512 + g * 8;

  f32x4 acc[4][2];
#pragma unroll
  for (int mt = 0; mt < 4; ++mt)
#pragma unroll
    for (int nt = 0; nt < 2; ++nt) acc[mt][nt] = (f32x4){0.f, 0.f, 0.f, 0.f};

  f16x8 af[4], bf[2];
#pragma unroll
  for (int mt = 0; mt < 4; ++mt) af[mt] = *(const f16x8*)ap[mt];
#pragma unroll
  for (int nt = 0; nt < 2; ++nt) bf[nt] = *(const f16x8*)bp[nt];

  for (int ks = 0; ks < 16; ++ks) {
    f16x8 an[4], bn[2];
    if (ks < 15) {
#pragma unroll
      for (int mt = 0; mt < 4; ++mt) an[mt] = *(const f16x8*)(ap[mt] + (ks + 1) * 32);
#pragma unroll
      for (int nt = 0; nt < 2; ++nt) bn[nt] = *(const f16x8*)(bp[nt] + (ks + 1) * 32);
    } else {
#pragma unroll
      for (int mt = 0; mt < 4; ++mt) an[mt] = af[mt];
#pragma unroll
      for (int nt = 0; nt < 2; ++nt) bn[nt] = bf[nt];
    }
#pragma unroll
    for (int mt = 0; mt < 4; ++mt)
#pragma unroll
      for (int nt = 0; nt < 2; ++nt)
        acc[mt][nt] = __builtin_amdgcn_mfma_f32_16x16x32_f16(af[mt], bf[nt], acc[mt][nt], 0, 0, 0);
#pragma unroll
    for (int mt = 0; mt < 4; ++mt) af[mt] = an[mt];
#pragma unroll
    for (int nt = 0; nt < 2; ++nt) bf[nt] = bn[nt];
  }

#pragma unroll
  for (int mt = 0; mt < 4; ++mt)
#pragma unroll
    for (int nt = 0; nt < 2; ++nt) {
      int col = ct * 64 + wc * 32 + nt * 16 + lane15;
      float bv = bvec[col];
#pragma unroll
      for (int i = 0; i < 4; ++i) {
        int row = rt * 128 + wr * 64 + mt * 16 + g * 4 + i;
        float val = acc[mt][nt][i] + bv;
        int bb_ = row >> 10, n = row & 1023, hh = col >> 5, d = col & 31;
        if (mode == 0) {
          ((unsigned short*)outp)[(size_t)row * 512 + col] = f2h(val);
        } else if (mode == 1) {
          ((unsigned short*)outp)[(((size_t)bb_ * 16 + hh) * 1024 + n) * 32 + d] = f2h(val);
        } else if (mode == 2) {
          ((unsigned short*)outp)[(((size_t)bb_ * 16 + hh) * 32 + d) * 1024 + n] = f2h(val);
        } else if (mode == 3) {
          ((float*)outp)[(size_t)row * 512 + col] = 1.f / (1.f + __expf(-val));
        } else {
          ((float*)outp)[(size_t)row * 512 + col] = gate[(size_t)row * 512 + col] * val;
        }
      }
    }
}

__global__ __launch_bounds__(256) void k_qkvg(const unsigned short* __restrict__ A,
                                              const unsigned short* __restrict__ T0, const unsigned short* __restrict__ T1,
                                              const unsigned short* __restrict__ T2, const unsigned short* __restrict__ T3,
                                              const float* __restrict__ b0, const float* __restrict__ b1,
                                              const float* __restrict__ b2, const float* __restrict__ b3,
                                              void* o0, void* o1, void* o2, void* o3) {
  int mode = blockIdx.z;
  const unsigned short* Wt = (mode == 0) ? T0 : (mode == 1) ? T1 : (mode == 2) ? T2 : T3;
  const float* bv = (mode == 0) ? b0 : (mode == 1) ? b1 : (mode == 2) ? b2 : b3;
  void* o = (mode == 0) ? o0 : (mode == 1) ? o1 : (mode == 2) ? o2 : o3;
  gemm_direct(A, Wt, bv, o, nullptr, mode, blockIdx.x, blockIdx.y);
}

__global__ __launch_bounds__(256) void k_gemm_out(const unsigned short* __restrict__ A,
                                                  const unsigned short* __restrict__ Wt,
                                                  const float* __restrict__ bvec,
                                                  float* __restrict__ outp,
                                                  const float* __restrict__ gate) {
  gemm_direct(A, Wt, bvec, outp, gate, 4, blockIdx.x, blockIdx.y);
}

// ---------------------------------------------------------------- fused z-stream + attention
// Grid 1024 = b*512 + pair (2 queries/block). 512 threads, 8 waves.
// LDS: sc[2][16][1024] f16 (64 KB) — scores in phase 1, P in phase 2.
// Phase 1: bias MFMA (lane15=h), NT z loads, masked sentinel, -> LDS swizzled.
// Phase 2: wave w owns heads 2w,2w+1 (both queries); lanes map to m (contiguous
// K/V); QK fdot2 + LDS score; full-row softmax; P->LDS; PV fdot2.
DEV unsigned scoff(int q, int h, int m) {
  return ((((unsigned)(q * 16 + h)) << 11) + (((unsigned)m) << 1)) ^ (((unsigned)(h & 7)) << 4);
}

__global__ __launch_bounds__(512, 4) void k_zsm(const float* __restrict__ z,
                                                const float* __restrict__ Wb,
                                                const float* __restrict__ bbp,
                                                const int* __restrict__ maskc,
                                                const unsigned short* __restrict__ qbuf,
                                                const unsigned short* __restrict__ kbuf,
                                                const unsigned short* __restrict__ vbuf,
                                                unsigned short* __restrict__ aout) {
  __shared__ unsigned short sc[2][16][1024];   // 64 KB exactly
  int bid = blockIdx.x;
  int b = bid >> 9, pair = bid & 511;
  int n0 = pair * 2;
  int t = threadIdx.x, l = t & 63, w = t >> 6;
  int lane15 = l & 15, g = l >> 4;
  const float RS = 0.17677669529663687f;  // 1/sqrt(32)
  const int* mrow = maskc + b * 1024;

  // ---- Phase 1: scores = z@Wb + bb (masked -> -65504), f16 into LDS
  {
    f16x8 wf[4];
#pragma unroll
    for (int ks = 0; ks < 4; ++ks)
#pragma unroll
      for (int j = 0; j < 8; ++j)
        wf[ks][j] = (_Float16)Wb[(ks * 32 + g * 8 + j) * 16 + lane15];
    float bbh = bbp[lane15];

#pragma unroll
    for (int q = 0; q < 2; ++q) {
      const float* zb = z + ((size_t)(b * 1024 + n0 + q)) * 1024 * 128;
      for (int t8 = 0; t8 < 8; ++t8) {
        int m0 = w * 128 + t8 * 16;
        const float* zr = zb + (size_t)(m0 + lane15) * 128 + g * 8;
        f32x4 acc = (f32x4){0.f, 0.f, 0.f, 0.f};
#pragma unroll
        for (int ks = 0; ks < 4; ++ks) {
          f32x4 z0 = __builtin_nontemporal_load((const f32x4*)(zr + ks * 32));
          f32x4 z1 = __builtin_nontemporal_load((const f32x4*)(zr + ks * 32 + 4));
          f16x8 af;
          af[0] = (_Float16)z0[0]; af[1] = (_Float16)z0[1];
          af[2] = (_Float16)z0[2]; af[3] = (_Float16)z0[3];
          af[4] = (_Float16)z1[0]; af[5] = (_Float16)z1[1];
          af[6] = (_Float16)z1[2]; af[7] = (_Float16)z1[3];
          acc = __builtin_amdgcn_mfma_f32_16x16x32_f16(af, wf[ks], acc, 0, 0, 0);
        }
        int m = m0 + 4 * g;
        int4 mk = *(const int4*)(mrow + m);
        ushort4 o4;
        o4.x = mk.x ? 0xFBFFu : f2h(acc[0] + bbh);
        o4.y = mk.y ? 0xFBFFu : f2h(acc[1] + bbh);
        o4.z = mk.z ? 0xFBFFu : f2h(acc[2] + bbh);
        o4.w = mk.w ? 0xFBFFu : f2h(acc[3] + bbh);
        *(ushort4*)((char*)sc + scoff(q, lane15, m)) = o4;
      }
    }
  }
  __syncthreads();

  // ---- Phase 2: wave w owns heads 2w, 2w+1 for both queries
#pragma unroll 1
  for (int hh = 0; hh < 2; ++hh) {
    int h = w * 2 + hh;
    unsigned qreg[2][16];
#pragma unroll
    for (int q = 0; q < 2; ++q) {
      const unsigned* qp = (const unsigned*)(qbuf + ((size_t)(b * 1024 + n0 + q)) * 512 + h * 32);
#pragma unroll
      for (int i = 0; i < 16; ++i) qreg[q][i] = qp[i];
    }
    const unsigned short* kb_ = kbuf + ((size_t)(b * 16 + h)) * 1024 * 32;

    // QK + score from LDS
    float s0[16], s1[16];
#pragma unroll 2
    for (int j = 0; j < 16; ++j) {
      int m = l + 64 * j;
      const uint4* kr = (const uint4*)(kb_ + (size_t)m * 32);
      uint4 k0 = kr[0], k1 = kr[1], k2 = kr[2], k3 = kr[3];
      float d0 = 0.f, d1 = 0.f;
      d0 = fdot2u(k0.x, qreg[0][0], d0);  d1 = fdot2u(k0.x, qreg[1][0], d1);
      d0 = fdot2u(k0.y, qreg[0][1], d0);  d1 = fdot2u(k0.y, qreg[1][1], d1);
      d0 = fdot2u(k0.z, qreg[0][2], d0);  d1 = fdot2u(k0.z, qreg[1][2], d1);
      d0 = fdot2u(k0.w, qreg[0][3], d0);  d1 = fdot2u(k0.w, qreg[1][3], d1);
      d0 = fdot2u(k1.x, qreg[0][4], d0);  d1 = fdot2u(k1.x, qreg[1][4], d1);
      d0 = fdot2u(k1.y, qreg[0][5], d0);  d1 = fdot2u(k1.y, qreg[1][5], d1);
      d0 = fdot2u(k1.z, qreg[0][6], d0);  d1 = fdot2u(k1.z, qreg[1][6], d1);
      d0 = fdot2u(k1.w, qreg[0][7], d0);  d1 = fdot2u(k1.w, qreg[1][7], d1);
      d0 = fdot2u(k2.x, qreg[0][8], d0);  d1 = fdot2u(k2.x, qreg[1][8], d1);
      d0 = fdot2u(k2.y, qreg[0][9], d0);  d1 = fdot2u(k2.y, qreg[1][9], d1);
      d0 = fdot2u(k2.z, qreg[0][10], d0); d1 = fdot2u(k2.z, qreg[1][10], d1);
      d0 = fdot2u(k2.w, qreg[0][11], d0); d1 = fdot2u(k2.w, qreg[1][11], d1);
      d0 = fdot2u(k3.x, qreg[0][12], d0); d1 = fdot2u(k3.x, qreg[1][12], d1);
      d0 = fdot2u(k3.y, qreg[0][13], d0); d1 = fdot2u(k3.y, qreg[1][13], d1);
      d0 = fdot2u(k3.z, qreg[0][14], d0); d1 = fdot2u(k3.z, qreg[1][14], d1);
      d0 = fdot2u(k3.w, qreg[0][15], d0); d1 = fdot2u(k3.w, qreg[1][15], d1);
      s0[j] = h2f(*(const unsigned short*)((const char*)sc + scoff(0, h, m))) + d0 * RS;
      s1[j] = h2f(*(const unsigned short*)((const char*)sc + scoff(1, h, m))) + d1 * RS;
    }

    // softmax per query; P back into LDS
    float minv[2];
#pragma unroll
    for (int q = 0; q < 2; ++q) {
      float* sv = q ? s1 : s0;
      float mx = -3.0e38f;
#pragma unroll
      for (int j = 0; j < 16; ++j) mx = fmaxf(mx, sv[j]);
#pragma unroll
      for (int off = 32; off >= 1; off >>= 1) mx = fmaxf(mx, __shfl_xor(mx, off));
      float sum = 0.f;
#pragma unroll
      for (int j = 0; j < 16; ++j) {
        float e = __expf(sv[j] - mx);
        sum += e;
        *(unsigned short*)((char*)sc + scoff(q, h, l + 64 * j)) = f2h(e);
      }
#pragma unroll
      for (int off = 32; off >= 1; off >>= 1) sum += __shfl_xor(sum, off);
      minv[q] = (mx > -30000.f && sum > 0.f) ? 1.f / sum : 0.f;
    }

    // PV: lane = (d = l&31, mh = l>>5); p reads are LDS broadcasts
    int d = l & 31, mh = l >> 5;
    const unsigned short* vr = vbuf + (((size_t)(b * 16 + h)) * 32 + d) * 1024 + mh * 512;
    unsigned pbase0 = ((unsigned)(0 * 16 + h)) << 11, pswz = ((unsigned)(h & 7)) << 4;
    unsigned pbase1 = ((unsigned)(1 * 16 + h)) << 11;
    unsigned moff = ((unsigned)(mh * 512)) << 1;
    float a0 = 0.f, a1 = 0.f;
    for (int i = 0; i < 64; ++i) {
      unsigned idx = (moff + i * 16) ^ pswz;
      uint4 v = *(const uint4*)(vr + i * 8);
      uint4 p0 = *(const uint4*)((const char*)sc + pbase0 + idx);
      uint4 p1 = *(const uint4*)((const char*)sc + pbase1 + idx);
      a0 = fdot2u(p0.x, v.x, a0);  a1 = fdot2u(p1.x, v.x, a1);
      a0 = fdot2u(p0.y, v.y, a0);  a1 = fdot2u(p1.y, v.y, a1);
      a0 = fdot2u(p0.z, v.z, a0);  a1 = fdot2u(p1.z, v.z, a1);
      a0 = fdot2u(p0.w, v.w, a0);  a1 = fdot2u(p1.w, v.w, a1);
    }
    a0 += __shfl_xor(a0, 32);
    a1 += __shfl_xor(a1, 32);
    if (mh == 0) {
      aout[((size_t)(b * 1024 + n0 + 0)) * 512 + h * 32 + d] = f2h(a0 * minv[0]);
      aout[((size_t)(b * 1024 + n0 + 1)) * 512 + h * 32 + d] = f2h(a1 * minv[1]);
    }
  }
}

// ----------------------------------------------------------------
extern "C" void kernel_launch(void* const* d_in, const int* in_sizes, int n_in,
                              void* d_out, int out_size, void* d_ws, size_t ws_size,
                              hipStream_t stream) {
  (void)in_sizes; (void)n_in; (void)out_size; (void)ws_size;
  const float* s     = (const float*)d_in[0];
  const float* z     = (const float*)d_in[1];
  const unsigned* km = (const unsigned*)d_in[2];
  const float* Wq = (const float*)d_in[3];
  const float* bq = (const float*)d_in[4];
  const float* Wk = (const float*)d_in[5];
  const float* bk = (const float*)d_in[6];
  const float* Wv = (const float*)d_in[7];
  const float* bv = (const float*)d_in[8];
  const float* Wb = (const float*)d_in[9];
  const float* bb = (const float*)d_in[10];
  const float* Wg = (const float*)d_in[11];
  const float* bg = (const float*)d_in[12];
  const float* Wo = (const float*)d_in[13];
  const float* bo = (const float*)d_in[14];
  const float* gamma = (const float*)d_in[15];
  const float* beta  = (const float*)d_in[16];

  char* ws = (char*)d_ws;
  unsigned short* sn    = (unsigned short*)(ws);                 // 2 MB
  unsigned short* qbuf  = (unsigned short*)(ws + (2ull << 20));  // 2 MB [b n][512]
  unsigned short* kbuf  = (unsigned short*)(ws + (4ull << 20));  // 2 MB [b][h][m][d]
  unsigned short* vbuf  = (unsigned short*)(ws + (6ull << 20));  // 2 MB [b][h][d][m]
  float*          gate  = (float*)(ws + (8ull << 20));           // 4 MB
  unsigned short* aout  = (unsigned short*)(ws + (12ull << 20)); // 2 MB
  int*            maskc = (int*)(ws + (78ull << 20));            // 8 KB
  unsigned short* wtq   = (unsigned short*)(ws + (80ull << 20)); // 512 KB each
  unsigned short* wtk   = (unsigned short*)(ws + (80ull << 20) + (512u << 10));
  unsigned short* wtv   = (unsigned short*)(ws + (80ull << 20) + (1024u << 10));
  unsigned short* wtg   = (unsigned short*)(ws + (80ull << 20) + (1536u << 10));
  unsigned short* wto   = (unsigned short*)(ws + (80ull << 20) + (2048u << 10));

  hipLaunchKernelGGL(k_prep, dim3(64, 5), dim3(256), 0, stream,
                     Wq, Wk, Wv, Wg, Wo, wtq, wtk, wtv, wtg, wto, km, maskc);
  hipLaunchKernelGGL(k_ln, dim3(2048), dim3(64), 0, stream, s, gamma, beta, sn);
  hipLaunchKernelGGL(k_qkvg, dim3(8, 16, 4), dim3(256), 0, stream, sn,
                     wtq, wtk, wtv, wtg, bq, bk, bv, bg,
                     (void*)qbuf, (void*)kbuf, (void*)vbuf, (void*)gate);
  hipLaunchKernelGGL(k_zsm, dim3(1024), dim3(512), 0, stream,
                     z, Wb, bb, maskc, qbuf, kbuf, vbuf, aout);
  hipLaunchKernelGGL(k_gemm_out, dim3(8, 16), dim3(256), 0, stream, aout, wto, bo,
                     (float*)d_out, gate);
}

// Round 10
// 295.095 us; speedup vs baseline: 1.6247x; 1.6247x over previous
//
#include <hip/hip_runtime.h>
#include <hip/hip_fp16.h>

typedef __attribute__((ext_vector_type(8))) _Float16 f16x8;
typedef __attribute__((ext_vector_type(8))) unsigned short u16x8;
typedef __attribute__((ext_vector_type(4))) float f32x4;

#define DEV __device__ __forceinline__

DEV unsigned short f2h(float f) {
  _Float16 h = (_Float16)f;
  return __builtin_bit_cast(unsigned short, h);
}
DEV float h2f(unsigned short u) {
  return (float)__builtin_bit_cast(_Float16, u);
}
DEV unsigned pk(float lo, float hi) {
  return (unsigned)f2h(lo) | ((unsigned)f2h(hi) << 16);
}

// ---------------------------------------------------------------- prep + LN:
// blockIdx.y in 0..4: transpose-convert W (f32 [k][col]) -> Wt (f16 [col][k]);
// blockIdx.y == 5: layernorm s -> sn (f16). Mask canon in (0,0).
__global__ __launch_bounds__(256) void k_prep(const float* __restrict__ W0, const float* __restrict__ W1,
                                              const float* __restrict__ W2, const float* __restrict__ W3,
                                              const float* __restrict__ W4,
                                              unsigned short* __restrict__ T0, unsigned short* __restrict__ T1,
                                              unsigned short* __restrict__ T2, unsigned short* __restrict__ T3,
                                              unsigned short* __restrict__ T4,
                                              const unsigned* __restrict__ raw, int* __restrict__ canon,
                                              const float* __restrict__ s,
                                              const float* __restrict__ gamma,
                                              const float* __restrict__ beta,
                                              unsigned short* __restrict__ sn) {
  int mat = blockIdx.y;
  int t = threadIdx.x;

  if (mat == 5) {
    // ---- layernorm: 64 blocks x 32 rows; team = t>>6 handles 8 rows
    int team = t >> 6, l = t & 63;
    float4 g0 = *(const float4*)(gamma + l * 8), g1 = *(const float4*)(gamma + l * 8 + 4);
    float4 b0 = *(const float4*)(beta + l * 8),  b1 = *(const float4*)(beta + l * 8 + 4);
#pragma unroll 2
    for (int i = 0; i < 8; ++i) {
      int row = blockIdx.x * 32 + team * 8 + i;
      const float* sr = s + (size_t)row * 512 + l * 8;
      float4 x0 = *(const float4*)sr, x1 = *(const float4*)(sr + 4);
      float sum = x0.x + x0.y + x0.z + x0.w + x1.x + x1.y + x1.z + x1.w;
      float sq  = x0.x*x0.x + x0.y*x0.y + x0.z*x0.z + x0.w*x0.w
                + x1.x*x1.x + x1.y*x1.y + x1.z*x1.z + x1.w*x1.w;
#pragma unroll
      for (int off = 32; off >= 1; off >>= 1) {
        sum += __shfl_xor(sum, off);
        sq  += __shfl_xor(sq, off);
      }
      float mu = sum * (1.f / 512.f);
      float rstd = rsqrtf(sq * (1.f / 512.f) - mu * mu + 1e-5f);
      u16x8 o;
      o[0] = f2h((x0.x - mu) * rstd * g0.x + b0.x);
      o[1] = f2h((x0.y - mu) * rstd * g0.y + b0.y);
      o[2] = f2h((x0.z - mu) * rstd * g0.z + b0.z);
      o[3] = f2h((x0.w - mu) * rstd * g0.w + b0.w);
      o[4] = f2h((x1.x - mu) * rstd * g1.x + b1.x);
      o[5] = f2h((x1.y - mu) * rstd * g1.y + b1.y);
      o[6] = f2h((x1.z - mu) * rstd * g1.z + b1.z);
      o[7] = f2h((x1.w - mu) * rstd * g1.w + b1.w);
      *(u16x8*)(sn + (size_t)row * 512 + l * 8) = o;
    }
    return;
  }

  const float* W = (mat == 0) ? W0 : (mat == 1) ? W1 : (mat == 2) ? W2 : (mat == 3) ? W3 : W4;
  unsigned short* T = (mat == 0) ? T0 : (mat == 1) ? T1 : (mat == 2) ? T2 : (mat == 3) ? T3 : T4;
  int tx = blockIdx.x & 7, ty = blockIdx.x >> 3;
  __shared__ float tile[64][65];
  int r = t >> 6, c = t & 63;
#pragma unroll
  for (int i = 0; i < 16; ++i)
    tile[r + i * 4][c] = W[(size_t)(ty * 64 + r + i * 4) * 512 + tx * 64 + c];
  __syncthreads();
#pragma unroll
  for (int i = 0; i < 16; ++i)
    T[(size_t)(tx * 64 + r + i * 4) * 512 + ty * 64 + c] = f2h(tile[c][r + i * 4]);

  if (mat == 0 && blockIdx.x == 0) {
    __shared__ int s_gt1, s_f32;
    if (t == 0) { s_gt1 = 0; s_f32 = 0; }
    __syncthreads();
    int gt1 = 0, fv = 0;
    for (int i = t; i < 512; i += 256) {
      unsigned v = raw[i];
      if (v == 0x3F800000u) fv = 1;
      else if (v > 1u) gt1 = 1;
    }
    if (gt1) s_gt1 = 1;
    if (fv)  s_f32 = 1;
    __syncthreads();
    int mode = s_gt1 ? 1 : (s_f32 ? 2 : 0);
    for (int i = t; i < 2048; i += 256) {
      int v;
      if (mode == 1)      v = ((const unsigned char*)raw)[i] ? 1 : 0;
      else if (mode == 2) v = (((const float*)raw)[i] != 0.f) ? 1 : 0;
      else                v = raw[i] ? 1 : 0;
      canon[i] = v;
    }
  }
}

// ---------------------------------------------------------------- direct-fragment GEMM
DEV void gemm_direct(const unsigned short* __restrict__ A,
                     const unsigned short* __restrict__ Wt,
                     const float* __restrict__ bvec,
                     void* __restrict__ outp,
                     const float* __restrict__ gate,
                     int mode, int ct, int rt) {
  int t = threadIdx.x, l = t & 63, w = t >> 6;
  int lane15 = l & 15, g = l >> 4;
  int wr = w >> 1, wc = w & 1;
  const unsigned short* ap[4];
  const unsigned short* bp[2];
#pragma unroll
  for (int mt = 0; mt < 4; ++mt)
    ap[mt] = A + (size_t)(rt * 128 + wr * 64 + mt * 16 + lane15) * 512 + g * 8;
#pragma unroll
  for (int nt = 0; nt < 2; ++nt)
    bp[nt] = Wt + (size_t)(ct * 64 + wc * 32 + nt * 16 + lane15) * 512 + g * 8;

  f32x4 acc[4][2];
#pragma unroll
  for (int mt = 0; mt < 4; ++mt)
#pragma unroll
    for (int nt = 0; nt < 2; ++nt) acc[mt][nt] = (f32x4){0.f, 0.f, 0.f, 0.f};

  f16x8 af[4], bf[2];
#pragma unroll
  for (int mt = 0; mt < 4; ++mt) af[mt] = *(const f16x8*)ap[mt];
#pragma unroll
  for (int nt = 0; nt < 2; ++nt) bf[nt] = *(const f16x8*)bp[nt];

  for (int ks = 0; ks < 16; ++ks) {
    f16x8 an[4], bn[2];
    if (ks < 15) {
#pragma unroll
      for (int mt = 0; mt < 4; ++mt) an[mt] = *(const f16x8*)(ap[mt] + (ks + 1) * 32);
#pragma unroll
      for (int nt = 0; nt < 2; ++nt) bn[nt] = *(const f16x8*)(bp[nt] + (ks + 1) * 32);
    } else {
#pragma unroll
      for (int mt = 0; mt < 4; ++mt) an[mt] = af[mt];
#pragma unroll
      for (int nt = 0; nt < 2; ++nt) bn[nt] = bf[nt];
    }
#pragma unroll
    for (int mt = 0; mt < 4; ++mt)
#pragma unroll
      for (int nt = 0; nt < 2; ++nt)
        acc[mt][nt] = __builtin_amdgcn_mfma_f32_16x16x32_f16(af[mt], bf[nt], acc[mt][nt], 0, 0, 0);
#pragma unroll
    for (int mt = 0; mt < 4; ++mt) af[mt] = an[mt];
#pragma unroll
    for (int nt = 0; nt < 2; ++nt) bf[nt] = bn[nt];
  }

#pragma unroll
  for (int mt = 0; mt < 4; ++mt)
#pragma unroll
    for (int nt = 0; nt < 2; ++nt) {
      int col = ct * 64 + wc * 32 + nt * 16 + lane15;
      float bv = bvec[col];
#pragma unroll
      for (int i = 0; i < 4; ++i) {
        int row = rt * 128 + wr * 64 + mt * 16 + g * 4 + i;
        float val = acc[mt][nt][i] + bv;
        int bb_ = row >> 10, n = row & 1023, hh = col >> 5, d = col & 31;
        if (mode == 0) {
          ((unsigned short*)outp)[(size_t)row * 512 + col] = f2h(val);
        } else if (mode == 1) {
          ((unsigned short*)outp)[(((size_t)bb_ * 16 + hh) * 1024 + n) * 32 + d] = f2h(val);
        } else if (mode == 2) {
          ((unsigned short*)outp)[(((size_t)bb_ * 16 + hh) * 32 + d) * 1024 + n] = f2h(val);
        } else if (mode == 3) {
          ((float*)outp)[(size_t)row * 512 + col] = 1.f / (1.f + __expf(-val));
        } else {
          ((float*)outp)[(size_t)row * 512 + col] = gate[(size_t)row * 512 + col] * val;
        }
      }
    }
}

__global__ __launch_bounds__(256) void k_qkvg(const unsigned short* __restrict__ A,
                                              const unsigned short* __restrict__ T0, const unsigned short* __restrict__ T1,
                                              const unsigned short* __restrict__ T2, const unsigned short* __restrict__ T3,
                                              const float* __restrict__ b0, const float* __restrict__ b1,
                                              const float* __restrict__ b2, const float* __restrict__ b3,
                                              void* o0, void* o1, void* o2, void* o3) {
  int mode = blockIdx.z;
  const unsigned short* Wt = (mode == 0) ? T0 : (mode == 1) ? T1 : (mode == 2) ? T2 : T3;
  const float* bv = (mode == 0) ? b0 : (mode == 1) ? b1 : (mode == 2) ? b2 : b3;
  void* o = (mode == 0) ? o0 : (mode == 1) ? o1 : (mode == 2) ? o2 : o3;
  gemm_direct(A, Wt, bv, o, nullptr, mode, blockIdx.x, blockIdx.y);
}

__global__ __launch_bounds__(256) void k_gemm_out(const unsigned short* __restrict__ A,
                                                  const unsigned short* __restrict__ Wt,
                                                  const float* __restrict__ bvec,
                                                  float* __restrict__ outp,
                                                  const float* __restrict__ gate) {
  gemm_direct(A, Wt, bvec, outp, gate, 4, blockIdx.x, blockIdx.y);
}

// ---------------------------------------------------------------- pair-bias stream
// bias[b][n][h][m] f16 = z[b,n,m,:]@Wb[:,h] + bb[h]; masked m -> -65504 sentinel.
// Wave-private LDS staging, no barriers; NONTEMPORAL z loads (zero reuse) keep
// the 64 MB bias buffer L3-resident across its write->read window (round-8 win).
__global__ __launch_bounds__(256, 4) void k_bias(const float* __restrict__ z,
                                                 const float* __restrict__ Wb,
                                                 const float* __restrict__ bbp,
                                                 const int* __restrict__ maskc,
                                                 unsigned short* __restrict__ bias) {
  int bid = blockIdx.x;             // 2*(b*1024+n) + half
  int slab = bid >> 1, half = bid & 1;
  int b = slab >> 10;
  int t = threadIdx.x, l = t & 63, w = t >> 6;
  int lane15 = l & 15, g = l >> 4;

  __shared__ float lds_[4][2048];   // 8 KB per wave
  float* wlds = lds_[w];

  f16x8 wf[4];
#pragma unroll
  for (int ks = 0; ks < 4; ++ks)
#pragma unroll
    for (int j = 0; j < 8; ++j)
      wf[ks][j] = (_Float16)Wb[(ks * 32 + g * 8 + j) * 16 + lane15];
  float bbh = bbp[lane15];

  const char* zb = (const char*)(z + ((size_t)slab * 1024 + half * 512 + (size_t)w * 128) * 128);
  unsigned short* ob = bias + ((size_t)slab * 16 + lane15) * 1024;
  const int* mrow = maskc + b * 1024;

  f32x4 rbuf[8];
#pragma unroll
  for (int i = 0; i < 8; ++i)
    rbuf[i] = __builtin_nontemporal_load((const f32x4*)(zb + i * 1024 + l * 16));
#pragma unroll
  for (int i = 0; i < 8; ++i) {
    int lin = i * 1024 + l * 16;
    int off = lin ^ (((lin >> 9) & 7) << 4);
    *(f32x4*)((char*)wlds + off) = rbuf[i];
  }

  for (int t8 = 0; t8 < 8; ++t8) {
    if (t8 < 7) {
      const char* tb = zb + (t8 + 1) * 8192;
#pragma unroll
      for (int i = 0; i < 8; ++i)
        rbuf[i] = __builtin_nontemporal_load((const f32x4*)(tb + i * 1024 + l * 16));
    }
    f32x4 acc = (f32x4){0.f, 0.f, 0.f, 0.f};
#pragma unroll
    for (int ks = 0; ks < 4; ++ks) {
      int linA = lane15 * 512 + ks * 128 + g * 32;
      int swz = ((lane15 & 7) << 4);
      f32x4 z0 = *(const f32x4*)((const char*)wlds + (linA ^ swz));
      f32x4 z1 = *(const f32x4*)((const char*)wlds + ((linA + 16) ^ swz));
      f16x8 af;
      af[0] = (_Float16)z0[0]; af[1] = (_Float16)z0[1];
      af[2] = (_Float16)z0[2]; af[3] = (_Float16)z0[3];
      af[4] = (_Float16)z1[0]; af[5] = (_Float16)z1[1];
      af[6] = (_Float16)z1[2]; af[7] = (_Float16)z1[3];
      acc = __builtin_amdgcn_mfma_f32_16x16x32_f16(af, wf[ks], acc, 0, 0, 0);
    }
    int mabs = half * 512 + w * 128 + t8 * 16 + 4 * g;
    int4 mk = *(const int4*)(mrow + mabs);
    ushort4 o4;
    o4.x = mk.x ? 0xFBFFu : f2h(acc[0] + bbh);
    o4.y = mk.y ? 0xFBFFu : f2h(acc[1] + bbh);
    o4.z = mk.z ? 0xFBFFu : f2h(acc[2] + bbh);
    o4.w = mk.w ? 0xFBFFu : f2h(acc[3] + bbh);
    *(ushort4*)(ob + mabs) = o4;
    if (t8 < 7) {
#pragma unroll
      for (int i = 0; i < 8; ++i) {
        int lin = i * 1024 + l * 16;
        int off = lin ^ (((lin >> 9) & 7) << 4);
        *(f32x4*)((char*)wlds + off) = rbuf[i];
      }
    }
  }
}

// ---------------------------------------------------------------- attention
// In-register flash, key-split (8 waves = 4 q-subtiles x 2 key-halves),
// software-pipelined chunk loads.
struct Pf {
  f16x8 kf1, kf2, vf1, vf2;
  ushort4 bv1, bv2;
};
DEV Pf ldchunk(const unsigned short* kb_, const unsigned short* vb_,
               const unsigned short* brow, int lane15, int g, int c) {
  Pf p;
  int m0 = c * 32;
  p.kf1 = *(const f16x8*)(kb_ + (size_t)(m0 + lane15) * 32 + g * 8);
  p.kf2 = *(const f16x8*)(kb_ + (size_t)(m0 + 16 + lane15) * 32 + g * 8);
  p.bv1 = *(const ushort4*)(brow + m0 + 4 * g);
  p.bv2 = *(const ushort4*)(brow + m0 + 16 + 4 * g);
  p.vf1 = *(const f16x8*)(vb_ + (size_t)lane15 * 1024 + m0 + 8 * g);
  p.vf2 = *(const f16x8*)(vb_ + (size_t)(16 + lane15) * 1024 + m0 + 8 * g);
  return p;
}

__global__ __launch_bounds__(512, 4) void k_attn(const unsigned short* __restrict__ qbuf,
                                                 const unsigned short* __restrict__ kbuf,
                                                 const unsigned short* __restrict__ vbuf,
                                                 const unsigned short* __restrict__ bias,
                                                 unsigned short* __restrict__ aout) {
  int qt = blockIdx.x, h = blockIdx.y, b = blockIdx.z;
  int t = threadIdx.x, l = t & 63, w = t >> 6;
  int qs = w & 3, half = w >> 2;
  int q0 = (qt * 4 + qs) * 16;
  int lane15 = l & 15, g = l >> 4;
  int bh = b * 16 + h;
  const float RS = 0.17677669529663687f;  // 1/sqrt(32)

  __shared__ float red_m[4][64];
  __shared__ float red_l[4][64];
  __shared__ f32x4 red_a1[4][64];
  __shared__ f32x4 red_a2[4][64];

  f16x8 qf = *(const f16x8*)(qbuf + ((size_t)(b * 1024 + q0 + lane15)) * 512 + h * 32 + g * 8);

  const unsigned short* kb_ = kbuf + (size_t)bh * 1024 * 32 + (size_t)half * 512 * 32;
  const unsigned short* vb_ = vbuf + (size_t)bh * 32 * 1024 + half * 512;
  const unsigned short* brow = bias + ((size_t)(b * 1024 + q0 + lane15) * 16 + h) * 1024 + half * 512;

  float m_run = -3.0e38f, lsum = 0.f;
  f32x4 acc1 = (f32x4){0.f, 0.f, 0.f, 0.f};
  f32x4 acc2 = (f32x4){0.f, 0.f, 0.f, 0.f};

  Pf cur = ldchunk(kb_, vb_, brow, lane15, g, 0);

  for (int c = 0; c < 16; ++c) {
    Pf nxt = cur;
    if (c < 15) nxt = ldchunk(kb_, vb_, brow, lane15, g, c + 1);

    f32x4 zero = (f32x4){0.f, 0.f, 0.f, 0.f};
    f32x4 c1 = __builtin_amdgcn_mfma_f32_16x16x32_f16(cur.kf1, qf, zero, 0, 0, 0);
    f32x4 c2 = __builtin_amdgcn_mfma_f32_16x16x32_f16(cur.kf2, qf, zero, 0, 0, 0);
    float s1[4], s2[4];
    s1[0] = c1[0] * RS + h2f(cur.bv1.x); s1[1] = c1[1] * RS + h2f(cur.bv1.y);
    s1[2] = c1[2] * RS + h2f(cur.bv1.z); s1[3] = c1[3] * RS + h2f(cur.bv1.w);
    s2[0] = c2[0] * RS + h2f(cur.bv2.x); s2[1] = c2[1] * RS + h2f(cur.bv2.y);
    s2[2] = c2[2] * RS + h2f(cur.bv2.z); s2[3] = c2[3] * RS + h2f(cur.bv2.w);
    float cm = fmaxf(fmaxf(fmaxf(s1[0], s1[1]), fmaxf(s1[2], s1[3])),
                     fmaxf(fmaxf(s2[0], s2[1]), fmaxf(s2[2], s2[3])));
    cm = fmaxf(cm, __shfl_xor(cm, 16));
    cm = fmaxf(cm, __shfl_xor(cm, 32));
    float mn = fmaxf(m_run, cm);
    float corr = __expf(m_run - mn);
    m_run = mn;
    float p1[4], p2[4], csum = 0.f;
#pragma unroll
    for (int i = 0; i < 4; ++i) { p1[i] = __expf(s1[i] - mn); csum += p1[i]; }
#pragma unroll
    for (int i = 0; i < 4; ++i) { p2[i] = __expf(s2[i] - mn); csum += p2[i]; }
    lsum = lsum * corr + csum;
#pragma unroll
    for (int i = 0; i < 4; ++i) { acc1[i] *= corr; acc2[i] *= corr; }
    unsigned a0 = pk(p1[0], p1[1]), a1 = pk(p1[2], p1[3]);
    unsigned b0 = pk(p2[0], p2[1]), b1 = pk(p2[2], p2[3]);
    int s0 = ((g & 1) << 5) + lane15, s1l = s0 + 16;
    unsigned wA0 = (unsigned)__shfl((int)a0, s0);
    unsigned wA1 = (unsigned)__shfl((int)a1, s0);
    unsigned wA2 = (unsigned)__shfl((int)a0, s1l);
    unsigned wA3 = (unsigned)__shfl((int)a1, s1l);
    unsigned wB0 = (unsigned)__shfl((int)b0, s0);
    unsigned wB1 = (unsigned)__shfl((int)b1, s0);
    unsigned wB2 = (unsigned)__shfl((int)b0, s1l);
    unsigned wB3 = (unsigned)__shfl((int)b1, s1l);
    bool hi = (l & 32) != 0;
    union { unsigned u[4]; f16x8 v; } pu;
    pu.u[0] = hi ? wB0 : wA0;
    pu.u[1] = hi ? wB1 : wA1;
    pu.u[2] = hi ? wB2 : wA2;
    pu.u[3] = hi ? wB3 : wA3;
    acc1 = __builtin_amdgcn_mfma_f32_16x16x32_f16(cur.vf1, pu.v, acc1, 0, 0, 0);
    acc2 = __builtin_amdgcn_mfma_f32_16x16x32_f16(cur.vf2, pu.v, acc2, 0, 0, 0);
    cur = nxt;
  }

  lsum += __shfl_xor(lsum, 16);
  lsum += __shfl_xor(lsum, 32);

  if (half) {
    red_m[qs][l] = m_run;
    red_l[qs][l] = lsum;
    red_a1[qs][l] = acc1;
    red_a2[qs][l] = acc2;
  }
  __syncthreads();
  if (!half) {
    float pm = red_m[qs][l], plv = red_l[qs][l];
    f32x4 pa1 = red_a1[qs][l], pa2 = red_a2[qs][l];
    float mm = fmaxf(m_run, pm);
    float c1s = __expf(m_run - mm), c2s = __expf(pm - mm);
    float lt = lsum * c1s + plv * c2s;
    float inv = (mm > -30000.f && lt > 0.f) ? 1.f / lt : 0.f;
    unsigned short* orow = aout + ((size_t)(b * 1024 + q0 + lane15)) * 512 + h * 32;
    ushort4 o1, o2;
    o1.x = f2h((acc1[0] * c1s + pa1[0] * c2s) * inv);
    o1.y = f2h((acc1[1] * c1s + pa1[1] * c2s) * inv);
    o1.z = f2h((acc1[2] * c1s + pa1[2] * c2s) * inv);
    o1.w = f2h((acc1[3] * c1s + pa1[3] * c2s) * inv);
    o2.x = f2h((acc2[0] * c1s + pa2[0] * c2s) * inv);
    o2.y = f2h((acc2[1] * c1s + pa2[1] * c2s) * inv);
    o2.z = f2h((acc2[2] * c1s + pa2[2] * c2s) * inv);
    o2.w = f2h((acc2[3] * c1s + pa2[3] * c2s) * inv);
    *(ushort4*)(orow + 4 * g) = o1;
    *(ushort4*)(orow + 16 + 4 * g) = o2;
  }
}

// ----------------------------------------------------------------
extern "C" void kernel_launch(void* const* d_in, const int* in_sizes, int n_in,
                              void* d_out, int out_size, void* d_ws, size_t ws_size,
                              hipStream_t stream) {
  (void)in_sizes; (void)n_in; (void)out_size; (void)ws_size;
  const float* s     = (const float*)d_in[0];
  const float* z     = (const float*)d_in[1];
  const unsigned* km = (const unsigned*)d_in[2];
  const float* Wq = (const float*)d_in[3];
  const float* bq = (const float*)d_in[4];
  const float* Wk = (const float*)d_in[5];
  const float* bk = (const float*)d_in[6];
  const float* Wv = (const float*)d_in[7];
  const float* bv = (const float*)d_in[8];
  const float* Wb = (const float*)d_in[9];
  const float* bb = (const float*)d_in[10];
  const float* Wg = (const float*)d_in[11];
  const float* bg = (const float*)d_in[12];
  const float* Wo = (const float*)d_in[13];
  const float* bo = (const float*)d_in[14];
  const float* gamma = (const float*)d_in[15];
  const float* beta  = (const float*)d_in[16];

  char* ws = (char*)d_ws;
  unsigned short* sn    = (unsigned short*)(ws);                 // 2 MB
  unsigned short* qbuf  = (unsigned short*)(ws + (2ull << 20));  // 2 MB [b n][512]
  unsigned short* kbuf  = (unsigned short*)(ws + (4ull << 20));  // 2 MB [b][h][m][d]
  unsigned short* vbuf  = (unsigned short*)(ws + (6ull << 20));  // 2 MB [b][h][d][m]
  float*          gate  = (float*)(ws + (8ull << 20));           // 4 MB
  unsigned short* aout  = (unsigned short*)(ws + (12ull << 20)); // 2 MB
  unsigned short* bias  = (unsigned short*)(ws + (14ull << 20)); // 64 MB [b][n][h][m]
  int*            maskc = (int*)(ws + (78ull << 20));            // 8 KB
  unsigned short* wtq   = (unsigned short*)(ws + (80ull << 20)); // 512 KB each
  unsigned short* wtk   = (unsigned short*)(ws + (80ull << 20) + (512u << 10));
  unsigned short* wtv   = (unsigned short*)(ws + (80ull << 20) + (1024u << 10));
  unsigned short* wtg   = (unsigned short*)(ws + (80ull << 20) + (1536u << 10));
  unsigned short* wto   = (unsigned short*)(ws + (80ull << 20) + (2048u << 10));

  hipLaunchKernelGGL(k_prep, dim3(64, 6), dim3(256), 0, stream,
                     Wq, Wk, Wv, Wg, Wo, wtq, wtk, wtv, wtg, wto, km, maskc,
                     s, gamma, beta, sn);
  hipLaunchKernelGGL(k_qkvg, dim3(8, 16, 4), dim3(256), 0, stream, sn,
                     wtq, wtk, wtv, wtg, bq, bk, bv, bg,
                     (void*)qbuf, (void*)kbuf, (void*)vbuf, (void*)gate);
  hipLaunchKernelGGL(k_bias, dim3(4096), dim3(256), 0, stream, z, Wb, bb, maskc, bias);
  hipLaunchKernelGGL(k_attn, dim3(16, 16, 2), dim3(512), 0, stream,
                     qbuf, kbuf, vbuf, bias, aout);
  hipLaunchKernelGGL(k_gemm_out, dim3(8, 16), dim3(256), 0, stream, aout, wto, bo,
                     (float*)d_out, gate);
}

// Round 11
// 290.843 us; speedup vs baseline: 1.6484x; 1.0146x over previous
//
#include <hip/hip_runtime.h>
#include <hip/hip_fp16.h>

typedef __attribute__((ext_vector_type(8))) _Float16 f16x8;
typedef __attribute__((ext_vector_type(8))) unsigned short u16x8;
typedef __attribute__((ext_vector_type(4))) float f32x4;

#define DEV __device__ __forceinline__

DEV unsigned short f2h(float f) {
  _Float16 h = (_Float16)f;
  return __builtin_bit_cast(unsigned short, h);
}
DEV float h2f(unsigned short u) {
  return (float)__builtin_bit_cast(_Float16, u);
}
DEV unsigned pk(float lo, float hi) {
  return (unsigned)f2h(lo) | ((unsigned)f2h(hi) << 16);
}

// ---------------------------------------------------------------- prep + LN:
// blockIdx.y in 0..4: transpose-convert W (f32 [k][col]) -> Wt (f16 [col][k]);
// blockIdx.y == 5: layernorm s -> sn (f16). Mask canon in (0,0).
__global__ __launch_bounds__(256) void k_prep(const float* __restrict__ W0, const float* __restrict__ W1,
                                              const float* __restrict__ W2, const float* __restrict__ W3,
                                              const float* __restrict__ W4,
                                              unsigned short* __restrict__ T0, unsigned short* __restrict__ T1,
                                              unsigned short* __restrict__ T2, unsigned short* __restrict__ T3,
                                              unsigned short* __restrict__ T4,
                                              const unsigned* __restrict__ raw, int* __restrict__ canon,
                                              const float* __restrict__ s,
                                              const float* __restrict__ gamma,
                                              const float* __restrict__ beta,
                                              unsigned short* __restrict__ sn) {
  int mat = blockIdx.y;
  int t = threadIdx.x;

  if (mat == 5) {
    int team = t >> 6, l = t & 63;
    float4 g0 = *(const float4*)(gamma + l * 8), g1 = *(const float4*)(gamma + l * 8 + 4);
    float4 b0 = *(const float4*)(beta + l * 8),  b1 = *(const float4*)(beta + l * 8 + 4);
#pragma unroll 2
    for (int i = 0; i < 8; ++i) {
      int row = blockIdx.x * 32 + team * 8 + i;
      const float* sr = s + (size_t)row * 512 + l * 8;
      float4 x0 = *(const float4*)sr, x1 = *(const float4*)(sr + 4);
      float sum = x0.x + x0.y + x0.z + x0.w + x1.x + x1.y + x1.z + x1.w;
      float sq  = x0.x*x0.x + x0.y*x0.y + x0.z*x0.z + x0.w*x0.w
                + x1.x*x1.x + x1.y*x1.y + x1.z*x1.z + x1.w*x1.w;
#pragma unroll
      for (int off = 32; off >= 1; off >>= 1) {
        sum += __shfl_xor(sum, off);
        sq  += __shfl_xor(sq, off);
      }
      float mu = sum * (1.f / 512.f);
      float rstd = rsqrtf(sq * (1.f / 512.f) - mu * mu + 1e-5f);
      u16x8 o;
      o[0] = f2h((x0.x - mu) * rstd * g0.x + b0.x);
      o[1] = f2h((x0.y - mu) * rstd * g0.y + b0.y);
      o[2] = f2h((x0.z - mu) * rstd * g0.z + b0.z);
      o[3] = f2h((x0.w - mu) * rstd * g0.w + b0.w);
      o[4] = f2h((x1.x - mu) * rstd * g1.x + b1.x);
      o[5] = f2h((x1.y - mu) * rstd * g1.y + b1.y);
      o[6] = f2h((x1.z - mu) * rstd * g1.z + b1.z);
      o[7] = f2h((x1.w - mu) * rstd * g1.w + b1.w);
      *(u16x8*)(sn + (size_t)row * 512 + l * 8) = o;
    }
    return;
  }

  const float* W = (mat == 0) ? W0 : (mat == 1) ? W1 : (mat == 2) ? W2 : (mat == 3) ? W3 : W4;
  unsigned short* T = (mat == 0) ? T0 : (mat == 1) ? T1 : (mat == 2) ? T2 : (mat == 3) ? T3 : T4;
  int tx = blockIdx.x & 7, ty = blockIdx.x >> 3;
  __shared__ float tile[64][65];
  int r = t >> 6, c = t & 63;
#pragma unroll
  for (int i = 0; i < 16; ++i)
    tile[r + i * 4][c] = W[(size_t)(ty * 64 + r + i * 4) * 512 + tx * 64 + c];
  __syncthreads();
#pragma unroll
  for (int i = 0; i < 16; ++i)
    T[(size_t)(tx * 64 + r + i * 4) * 512 + ty * 64 + c] = f2h(tile[c][r + i * 4]);

  if (mat == 0 && blockIdx.x == 0) {
    __shared__ int s_gt1, s_f32;
    if (t == 0) { s_gt1 = 0; s_f32 = 0; }
    __syncthreads();
    int gt1 = 0, fv = 0;
    for (int i = t; i < 512; i += 256) {
      unsigned v = raw[i];
      if (v == 0x3F800000u) fv = 1;
      else if (v > 1u) gt1 = 1;
    }
    if (gt1) s_gt1 = 1;
    if (fv)  s_f32 = 1;
    __syncthreads();
    int mode = s_gt1 ? 1 : (s_f32 ? 2 : 0);
    for (int i = t; i < 2048; i += 256) {
      int v;
      if (mode == 1)      v = ((const unsigned char*)raw)[i] ? 1 : 0;
      else if (mode == 2) v = (((const float*)raw)[i] != 0.f) ? 1 : 0;
      else                v = raw[i] ? 1 : 0;
      canon[i] = v;
    }
  }
}

// ---------------------------------------------------------------- direct-fragment GEMM
DEV void gemm_direct(const unsigned short* __restrict__ A,
                     const unsigned short* __restrict__ Wt,
                     const float* __restrict__ bvec,
                     void* __restrict__ outp,
                     const float* __restrict__ gate,
                     int mode, int ct, int rt) {
  int t = threadIdx.x, l = t & 63, w = t >> 6;
  int lane15 = l & 15, g = l >> 4;
  int wr = w >> 1, wc = w & 1;
  const unsigned short* ap[4];
  const unsigned short* bp[2];
#pragma unroll
  for (int mt = 0; mt < 4; ++mt)
    ap[mt] = A + (size_t)(rt * 128 + wr * 64 + mt * 16 + lane15) * 512 + g * 8;
#pragma unroll
  for (int nt = 0; nt < 2; ++nt)
    bp[nt] = Wt + (size_t)(ct * 64 + wc * 32 + nt * 16 + lane15) * 512 + g * 8;

  f32x4 acc[4][2];
#pragma unroll
  for (int mt = 0; mt < 4; ++mt)
#pragma unroll
    for (int nt = 0; nt < 2; ++nt) acc[mt][nt] = (f32x4){0.f, 0.f, 0.f, 0.f};

  f16x8 af[4], bf[2];
#pragma unroll
  for (int mt = 0; mt < 4; ++mt) af[mt] = *(const f16x8*)ap[mt];
#pragma unroll
  for (int nt = 0; nt < 2; ++nt) bf[nt] = *(const f16x8*)bp[nt];

  for (int ks = 0; ks < 16; ++ks) {
    f16x8 an[4], bn[2];
    if (ks < 15) {
#pragma unroll
      for (int mt = 0; mt < 4; ++mt) an[mt] = *(const f16x8*)(ap[mt] + (ks + 1) * 32);
#pragma unroll
      for (int nt = 0; nt < 2; ++nt) bn[nt] = *(const f16x8*)(bp[nt] + (ks + 1) * 32);
    } else {
#pragma unroll
      for (int mt = 0; mt < 4; ++mt) an[mt] = af[mt];
#pragma unroll
      for (int nt = 0; nt < 2; ++nt) bn[nt] = bf[nt];
    }
#pragma unroll
    for (int mt = 0; mt < 4; ++mt)
#pragma unroll
      for (int nt = 0; nt < 2; ++nt)
        acc[mt][nt] = __builtin_amdgcn_mfma_f32_16x16x32_f16(af[mt], bf[nt], acc[mt][nt], 0, 0, 0);
#pragma unroll
    for (int mt = 0; mt < 4; ++mt) af[mt] = an[mt];
#pragma unroll
    for (int nt = 0; nt < 2; ++nt) bf[nt] = bn[nt];
  }

#pragma unroll
  for (int mt = 0; mt < 4; ++mt)
#pragma unroll
    for (int nt = 0; nt < 2; ++nt) {
      int col = ct * 64 + wc * 32 + nt * 16 + lane15;
      float bv = bvec[col];
#pragma unroll
      for (int i = 0; i < 4; ++i) {
        int row = rt * 128 + wr * 64 + mt * 16 + g * 4 + i;
        float val = acc[mt][nt][i] + bv;
        int bb_ = row >> 10, n = row & 1023, hh = col >> 5, d = col & 31;
        if (mode == 0) {
          ((unsigned short*)outp)[(size_t)row * 512 + col] = f2h(val);
        } else if (mode == 1) {
          ((unsigned short*)outp)[(((size_t)bb_ * 16 + hh) * 1024 + n) * 32 + d] = f2h(val);
        } else if (mode == 2) {
          ((unsigned short*)outp)[(((size_t)bb_ * 16 + hh) * 32 + d) * 1024 + n] = f2h(val);
        } else if (mode == 3) {
          ((float*)outp)[(size_t)row * 512 + col] = 1.f / (1.f + __expf(-val));
        } else {
          ((float*)outp)[(size_t)row * 512 + col] = gate[(size_t)row * 512 + col] * val;
        }
      }
    }
}

__global__ __launch_bounds__(256) void k_gemm_out(const unsigned short* __restrict__ A,
                                                  const unsigned short* __restrict__ Wt,
                                                  const float* __restrict__ bvec,
                                                  float* __restrict__ outp,
                                                  const float* __restrict__ gate) {
  gemm_direct(A, Wt, bvec, outp, gate, 4, blockIdx.x, blockIdx.y);
}

// ---------------------------------------------------------------- pair-bias stream + QKVG tail
// bid < 4096: bias[b][n][h][m] f16 = z@Wb + bb (masked -> -65504), NT z loads,
//             wave-private LDS staging (round-8/10 proven path).
// bid >= 4096: heterogeneous tail = the 4 projection GEMMs (q/k/v/gate), hidden
//             inside the BW-bound z-stream (both depend only on k_prep).
__global__ __launch_bounds__(256, 4) void k_biasq(const float* __restrict__ z,
                                                  const float* __restrict__ Wb,
                                                  const float* __restrict__ bbp,
                                                  const int* __restrict__ maskc,
                                                  unsigned short* __restrict__ bias,
                                                  const unsigned short* __restrict__ A,
                                                  const unsigned short* __restrict__ T0,
                                                  const unsigned short* __restrict__ T1,
                                                  const unsigned short* __restrict__ T2,
                                                  const unsigned short* __restrict__ T3,
                                                  const float* __restrict__ pb0, const float* __restrict__ pb1,
                                                  const float* __restrict__ pb2, const float* __restrict__ pb3,
                                                  void* o0, void* o1, void* o2, void* o3) {
  int bid = blockIdx.x;

  if (bid >= 4096) {               // ---- projection-GEMM tail blocks
    int id = bid - 4096;           // 512 blocks: mode*128 + rt*8 + ct
    int mode = id >> 7, rem = id & 127;
    int ct = rem & 7, rt = rem >> 3;
    const unsigned short* Wt = (mode == 0) ? T0 : (mode == 1) ? T1 : (mode == 2) ? T2 : T3;
    const float* bv = (mode == 0) ? pb0 : (mode == 1) ? pb1 : (mode == 2) ? pb2 : pb3;
    void* o = (mode == 0) ? o0 : (mode == 1) ? o1 : (mode == 2) ? o2 : o3;
    gemm_direct(A, Wt, bv, o, nullptr, mode, ct, rt);
    return;
  }

  int slab = bid >> 1, half = bid & 1;
  int b = slab >> 10;
  int t = threadIdx.x, l = t & 63, w = t >> 6;
  int lane15 = l & 15, g = l >> 4;

  __shared__ float lds_[4][2048];   // 8 KB per wave
  float* wlds = lds_[w];

  f16x8 wf[4];
#pragma unroll
  for (int ks = 0; ks < 4; ++ks)
#pragma unroll
    for (int j = 0; j < 8; ++j)
      wf[ks][j] = (_Float16)Wb[(ks * 32 + g * 8 + j) * 16 + lane15];
  float bbh = bbp[lane15];

  const char* zb = (const char*)(z + ((size_t)slab * 1024 + half * 512 + (size_t)w * 128) * 128);
  unsigned short* ob = bias + ((size_t)slab * 16 + lane15) * 1024;
  const int* mrow = maskc + b * 1024;

  f32x4 rbuf[8];
#pragma unroll
  for (int i = 0; i < 8; ++i)
    rbuf[i] = __builtin_nontemporal_load((const f32x4*)(zb + i * 1024 + l * 16));
#pragma unroll
  for (int i = 0; i < 8; ++i) {
    int lin = i * 1024 + l * 16;
    int off = lin ^ (((lin >> 9) & 7) << 4);
    *(f32x4*)((char*)wlds + off) = rbuf[i];
  }

  for (int t8 = 0; t8 < 8; ++t8) {
    if (t8 < 7) {
      const char* tb = zb + (t8 + 1) * 8192;
#pragma unroll
      for (int i = 0; i < 8; ++i)
        rbuf[i] = __builtin_nontemporal_load((const f32x4*)(tb + i * 1024 + l * 16));
    }
    f32x4 acc = (f32x4){0.f, 0.f, 0.f, 0.f};
#pragma unroll
    for (int ks = 0; ks < 4; ++ks) {
      int linA = lane15 * 512 + ks * 128 + g * 32;
      int swz = ((lane15 & 7) << 4);
      f32x4 z0 = *(const f32x4*)((const char*)wlds + (linA ^ swz));
      f32x4 z1 = *(const f32x4*)((const char*)wlds + ((linA + 16) ^ swz));
      f16x8 af;
      af[0] = (_Float16)z0[0]; af[1] = (_Float16)z0[1];
      af[2] = (_Float16)z0[2]; af[3] = (_Float16)z0[3];
      af[4] = (_Float16)z1[0]; af[5] = (_Float16)z1[1];
      af[6] = (_Float16)z1[2]; af[7] = (_Float16)z1[3];
      acc = __builtin_amdgcn_mfma_f32_16x16x32_f16(af, wf[ks], acc, 0, 0, 0);
    }
    int mabs = half * 512 + w * 128 + t8 * 16 + 4 * g;
    int4 mk = *(const int4*)(mrow + mabs);
    ushort4 o4;
    o4.x = mk.x ? 0xFBFFu : f2h(acc[0] + bbh);
    o4.y = mk.y ? 0xFBFFu : f2h(acc[1] + bbh);
    o4.z = mk.z ? 0xFBFFu : f2h(acc[2] + bbh);
    o4.w = mk.w ? 0xFBFFu : f2h(acc[3] + bbh);
    *(ushort4*)(ob + mabs) = o4;
    if (t8 < 7) {
#pragma unroll
      for (int i = 0; i < 8; ++i) {
        int lin = i * 1024 + l * 16;
        int off = lin ^ (((lin >> 9) & 7) << 4);
        *(f32x4*)((char*)wlds + off) = rbuf[i];
      }
    }
  }
}

// ---------------------------------------------------------------- attention
// In-register flash, key-split (8 waves = 4 q-subtiles x 2 key-halves),
// software-pipelined chunk loads.
struct Pf {
  f16x8 kf1, kf2, vf1, vf2;
  ushort4 bv1, bv2;
};
DEV Pf ldchunk(const unsigned short* kb_, const unsigned short* vb_,
               const unsigned short* brow, int lane15, int g, int c) {
  Pf p;
  int m0 = c * 32;
  p.kf1 = *(const f16x8*)(kb_ + (size_t)(m0 + lane15) * 32 + g * 8);
  p.kf2 = *(const f16x8*)(kb_ + (size_t)(m0 + 16 + lane15) * 32 + g * 8);
  p.bv1 = *(const ushort4*)(brow + m0 + 4 * g);
  p.bv2 = *(const ushort4*)(brow + m0 + 16 + 4 * g);
  p.vf1 = *(const f16x8*)(vb_ + (size_t)lane15 * 1024 + m0 + 8 * g);
  p.vf2 = *(const f16x8*)(vb_ + (size_t)(16 + lane15) * 1024 + m0 + 8 * g);
  return p;
}

__global__ __launch_bounds__(512, 4) void k_attn(const unsigned short* __restrict__ qbuf,
                                                 const unsigned short* __restrict__ kbuf,
                                                 const unsigned short* __restrict__ vbuf,
                                                 const unsigned short* __restrict__ bias,
                                                 unsigned short* __restrict__ aout) {
  int qt = blockIdx.x, h = blockIdx.y, b = blockIdx.z;
  int t = threadIdx.x, l = t & 63, w = t >> 6;
  int qs = w & 3, half = w >> 2;
  int q0 = (qt * 4 + qs) * 16;
  int lane15 = l & 15, g = l >> 4;
  int bh = b * 16 + h;
  const float RS = 0.17677669529663687f;  // 1/sqrt(32)

  __shared__ float red_m[4][64];
  __shared__ float red_l[4][64];
  __shared__ f32x4 red_a1[4][64];
  __shared__ f32x4 red_a2[4][64];

  f16x8 qf = *(const f16x8*)(qbuf + ((size_t)(b * 1024 + q0 + lane15)) * 512 + h * 32 + g * 8);

  const unsigned short* kb_ = kbuf + (size_t)bh * 1024 * 32 + (size_t)half * 512 * 32;
  const unsigned short* vb_ = vbuf + (size_t)bh * 32 * 1024 + half * 512;
  const unsigned short* brow = bias + ((size_t)(b * 1024 + q0 + lane15) * 16 + h) * 1024 + half * 512;

  float m_run = -3.0e38f, lsum = 0.f;
  f32x4 acc1 = (f32x4){0.f, 0.f, 0.f, 0.f};
  f32x4 acc2 = (f32x4){0.f, 0.f, 0.f, 0.f};

  Pf cur = ldchunk(kb_, vb_, brow, lane15, g, 0);

  for (int c = 0; c < 16; ++c) {
    Pf nxt = cur;
    if (c < 15) nxt = ldchunk(kb_, vb_, brow, lane15, g, c + 1);

    f32x4 zero = (f32x4){0.f, 0.f, 0.f, 0.f};
    f32x4 c1 = __builtin_amdgcn_mfma_f32_16x16x32_f16(cur.kf1, qf, zero, 0, 0, 0);
    f32x4 c2 = __builtin_amdgcn_mfma_f32_16x16x32_f16(cur.kf2, qf, zero, 0, 0, 0);
    float s1[4], s2[4];
    s1[0] = c1[0] * RS + h2f(cur.bv1.x); s1[1] = c1[1] * RS + h2f(cur.bv1.y);
    s1[2] = c1[2] * RS + h2f(cur.bv1.z); s1[3] = c1[3] * RS + h2f(cur.bv1.w);
    s2[0] = c2[0] * RS + h2f(cur.bv2.x); s2[1] = c2[1] * RS + h2f(cur.bv2.y);
    s2[2] = c2[2] * RS + h2f(cur.bv2.z); s2[3] = c2[3] * RS + h2f(cur.bv2.w);
    float cm = fmaxf(fmaxf(fmaxf(s1[0], s1[1]), fmaxf(s1[2], s1[3])),
                     fmaxf(fmaxf(s2[0], s2[1]), fmaxf(s2[2], s2[3])));
    cm = fmaxf(cm, __shfl_xor(cm, 16));
    cm = fmaxf(cm, __shfl_xor(cm, 32));
    float mn = fmaxf(m_run, cm);
    float corr = __expf(m_run - mn);
    m_run = mn;
    float p1[4], p2[4], csum = 0.f;
#pragma unroll
    for (int i = 0; i < 4; ++i) { p1[i] = __expf(s1[i] - mn); csum += p1[i]; }
#pragma unroll
    for (int i = 0; i < 4; ++i) { p2[i] = __expf(s2[i] - mn); csum += p2[i]; }
    lsum = lsum * corr + csum;
#pragma unroll
    for (int i = 0; i < 4; ++i) { acc1[i] *= corr; acc2[i] *= corr; }
    unsigned a0 = pk(p1[0], p1[1]), a1 = pk(p1[2], p1[3]);
    unsigned b0 = pk(p2[0], p2[1]), b1 = pk(p2[2], p2[3]);
    int s0 = ((g & 1) << 5) + lane15, s1l = s0 + 16;
    unsigned wA0 = (unsigned)__shfl((int)a0, s0);
    unsigned wA1 = (unsigned)__shfl((int)a1, s0);
    unsigned wA2 = (unsigned)__shfl((int)a0, s1l);
    unsigned wA3 = (unsigned)__shfl((int)a1, s1l);
    unsigned wB0 = (unsigned)__shfl((int)b0, s0);
    unsigned wB1 = (unsigned)__shfl((int)b1, s0);
    unsigned wB2 = (unsigned)__shfl((int)b0, s1l);
    unsigned wB3 = (unsigned)__shfl((int)b1, s1l);
    bool hi = (l & 32) != 0;
    union { unsigned u[4]; f16x8 v; } pu;
    pu.u[0] = hi ? wB0 : wA0;
    pu.u[1] = hi ? wB1 : wA1;
    pu.u[2] = hi ? wB2 : wA2;
    pu.u[3] = hi ? wB3 : wA3;
    acc1 = __builtin_amdgcn_mfma_f32_16x16x32_f16(cur.vf1, pu.v, acc1, 0, 0, 0);
    acc2 = __builtin_amdgcn_mfma_f32_16x16x32_f16(cur.vf2, pu.v, acc2, 0, 0, 0);
    cur = nxt;
  }

  lsum += __shfl_xor(lsum, 16);
  lsum += __shfl_xor(lsum, 32);

  if (half) {
    red_m[qs][l] = m_run;
    red_l[qs][l] = lsum;
    red_a1[qs][l] = acc1;
    red_a2[qs][l] = acc2;
  }
  __syncthreads();
  if (!half) {
    float pm = red_m[qs][l], plv = red_l[qs][l];
    f32x4 pa1 = red_a1[qs][l], pa2 = red_a2[qs][l];
    float mm = fmaxf(m_run, pm);
    float c1s = __expf(m_run - mm), c2s = __expf(pm - mm);
    float lt = lsum * c1s + plv * c2s;
    float inv = (mm > -30000.f && lt > 0.f) ? 1.f / lt : 0.f;
    unsigned short* orow = aout + ((size_t)(b * 1024 + q0 + lane15)) * 512 + h * 32;
    ushort4 o1, o2;
    o1.x = f2h((acc1[0] * c1s + pa1[0] * c2s) * inv);
    o1.y = f2h((acc1[1] * c1s + pa1[1] * c2s) * inv);
    o1.z = f2h((acc1[2] * c1s + pa1[2] * c2s) * inv);
    o1.w = f2h((acc1[3] * c1s + pa1[3] * c2s) * inv);
    o2.x = f2h((acc2[0] * c1s + pa2[0] * c2s) * inv);
    o2.y = f2h((acc2[1] * c1s + pa2[1] * c2s) * inv);
    o2.z = f2h((acc2[2] * c1s + pa2[2] * c2s) * inv);
    o2.w = f2h((acc2[3] * c1s + pa2[3] * c2s) * inv);
    *(ushort4*)(orow + 4 * g) = o1;
    *(ushort4*)(orow + 16 + 4 * g) = o2;
  }
}

// ----------------------------------------------------------------
extern "C" void kernel_launch(void* const* d_in, const int* in_sizes, int n_in,
                              void* d_out, int out_size, void* d_ws, size_t ws_size,
                              hipStream_t stream) {
  (void)in_sizes; (void)n_in; (void)out_size; (void)ws_size;
  const float* s     = (const float*)d_in[0];
  const float* z     = (const float*)d_in[1];
  const unsigned* km = (const unsigned*)d_in[2];
  const float* Wq = (const float*)d_in[3];
  const float* bq = (const float*)d_in[4];
  const float* Wk = (const float*)d_in[5];
  const float* bk = (const float*)d_in[6];
  const float* Wv = (const float*)d_in[7];
  const float* bv = (const float*)d_in[8];
  const float* Wb = (const float*)d_in[9];
  const float* bb = (const float*)d_in[10];
  const float* Wg = (const float*)d_in[11];
  const float* bg = (const float*)d_in[12];
  const float* Wo = (const float*)d_in[13];
  const float* bo = (const float*)d_in[14];
  const float* gamma = (const float*)d_in[15];
  const float* beta  = (const float*)d_in[16];

  char* ws = (char*)d_ws;
  unsigned short* sn    = (unsigned short*)(ws);                 // 2 MB
  unsigned short* qbuf  = (unsigned short*)(ws + (2ull << 20));  // 2 MB [b n][512]
  unsigned short* kbuf  = (unsigned short*)(ws + (4ull << 20));  // 2 MB [b][h][m][d]
  unsigned short* vbuf  = (unsigned short*)(ws + (6ull << 20));  // 2 MB [b][h][d][m]
  float*          gate  = (float*)(ws + (8ull << 20));           // 4 MB
  unsigned short* aout  = (unsigned short*)(ws + (12ull << 20)); // 2 MB
  unsigned short* bias  = (unsigned short*)(ws + (14ull << 20)); // 64 MB [b][n][h][m]
  int*            maskc = (int*)(ws + (78ull << 20));            // 8 KB
  unsigned short* wtq   = (unsigned short*)(ws + (80ull << 20)); // 512 KB each
  unsigned short* wtk   = (unsigned short*)(ws + (80ull << 20) + (512u << 10));
  unsigned short* wtv   = (unsigned short*)(ws + (80ull << 20) + (1024u << 10));
  unsigned short* wtg   = (unsigned short*)(ws + (80ull << 20) + (1536u << 10));
  unsigned short* wto   = (unsigned short*)(ws + (80ull << 20) + (2048u << 10));

  hipLaunchKernelGGL(k_prep, dim3(64, 6), dim3(256), 0, stream,
                     Wq, Wk, Wv, Wg, Wo, wtq, wtk, wtv, wtg, wto, km, maskc,
                     s, gamma, beta, sn);
  hipLaunchKernelGGL(k_biasq, dim3(4608), dim3(256), 0, stream,
                     z, Wb, bb, maskc, bias,
                     sn, wtq, wtk, wtv, wtg, bq, bk, bv, bg,
                     (void*)qbuf, (void*)kbuf, (void*)vbuf, (void*)gate);
  hipLaunchKernelGGL(k_attn, dim3(16, 16, 2), dim3(512), 0, stream,
                     qbuf, kbuf, vbuf, bias, aout);
  hipLaunchKernelGGL(k_gemm_out, dim3(8, 16), dim3(256), 0, stream, aout, wto, bo,
                     (float*)d_out, gate);
}